// Round 1
// baseline (111.730 us; speedup 1.0000x reference)
//
#include <hip/hip_runtime.h>
#include <math.h>

#define Bn 4
#define Hn 512
#define Wn 229
#define Cn 32
#define OUTn 88
#define BH (Bn*Hn)            // 2048
#define NPOS (BH*Wn)          // 468992 = 1832 * 256 exactly
#define FP_SIZE (BH*OUTn)     // 180224
#define CW (Cn*Wn)            // 7328

// workspace layout (float offsets)
#define WS_SCAL 0             // 7 floats: A, Rt[0..2], Rf[0..2]
#define WS_WEFF 16            // Wn*OUTn = 20152 floats, layout [w][o]
#define WS_O    (16 + Wn*OUTn) // Wn*BH = 468992 floats, layout [w][bh]

// ---------------- kernel 1: scalars + effective head matrix ----------------
__global__ __launch_bounds__(256) void prep_kernel(
    const float* __restrict__ Wq, const float* __restrict__ Wk,
    const float* __restrict__ Wv, const float* __restrict__ rel_t,
    const float* __restrict__ rel_f, const float* __restrict__ W_lin,
    float* __restrict__ ws) {
  int tid = blockIdx.x * 256 + threadIdx.x;
  if (tid == 0) {
    float A = 0.f;
    for (int c = 0; c < Cn; ++c) A += Wq[c] * Wk[c];
    ws[WS_SCAL + 0] = A;
    for (int i = 0; i < 3; ++i) {
      float rt = 0.f, rf = 0.f;
      for (int c = 0; c < 16; ++c) {
        rt += Wq[c]      * rel_t[c*3 + i];
        rf += Wq[16 + c] * rel_f[c*3 + i];
      }
      ws[WS_SCAL + 1 + i] = rt;
      ws[WS_SCAL + 4 + i] = rf;
    }
  }
  if (tid < Wn * OUTn) {
    int w = tid / OUTn;
    int o = tid - w * OUTn;
    float acc = 0.f;
    #pragma unroll
    for (int c = 0; c < Cn; ++c) acc += W_lin[o*CW + c*Wn + w] * Wv[c];
    ws[WS_WEFF + tid] = acc;   // WeffT[w][o], coalesced write
  }
}

// ---------------- kernel 2: per-position attention ----------------
__global__ __launch_bounds__(256) void attn_kernel(
    const float* __restrict__ spec, const float* __restrict__ ws,
    float* __restrict__ out, float* __restrict__ o_ws) {
  __shared__ float satt[256 * 9];
  const int idx = blockIdx.x * 256 + threadIdx.x;   // = bh*Wn + w
  const int bh  = idx / Wn;
  const int w   = idx - bh * Wn;
  const int h   = bh & (Hn - 1);

  const float A  = ws[WS_SCAL + 0];
  const float s  = spec[idx];

  float e[9], sp[9];
  float m = -1e30f;
  #pragma unroll
  for (int i = 0; i < 3; ++i) {
    const int hh = h + i - 1;
    const bool hin = (unsigned)hh < (unsigned)Hn;
    const float rt = ws[WS_SCAL + 1 + i];
    #pragma unroll
    for (int j = 0; j < 3; ++j) {
      const int ww = w + j - 1;
      const bool in = hin && ((unsigned)ww < (unsigned)Wn);
      const int k = i*3 + j;
      const float v = in ? spec[idx + (i-1)*Wn + (j-1)] : 0.f;
      sp[k] = v;
      const float ek = s * (A*v + rt + ws[WS_SCAL + 4 + j]);
      e[k] = ek;
      m = fmaxf(m, ek);
    }
  }
  float sum = 0.f;
  #pragma unroll
  for (int k = 0; k < 9; ++k) { e[k] = __expf(e[k] - m); sum += e[k]; }
  const float inv = 1.f / sum;
  float o = 0.f;
  #pragma unroll
  for (int k = 0; k < 9; ++k) {
    const float a = e[k] * inv;
    satt[threadIdx.x * 9 + k] = a;
    o += a * sp[k];
  }
  o_ws[w * BH + bh] = o;   // transposed store for head kernel

  __syncthreads();
  float* dst = out + FP_SIZE + (size_t)blockIdx.x * (256 * 9);
  #pragma unroll
  for (int k = 0; k < 9; ++k)
    dst[k * 256 + threadIdx.x] = satt[k * 256 + threadIdx.x];  // coalesced
}

// ---------------- kernel 3: frame head ----------------
__global__ __launch_bounds__(256) void head_kernel(
    const float* __restrict__ ws, const float* __restrict__ b_lin,
    float* __restrict__ out) {
  const int og = blockIdx.x % 11;                 // 11 groups of 8 outputs
  const int bh = (blockIdx.x / 11) * 256 + threadIdx.x;
  const float* WeffT = ws + WS_WEFF;
  const float* ovec  = ws + WS_O;

  float acc[8];
  #pragma unroll
  for (int u = 0; u < 8; ++u) acc[u] = b_lin[og*8 + u];

  for (int w = 0; w < Wn; ++w) {
    const float x = ovec[w * BH + bh];            // coalesced
    const float* wr = WeffT + w * OUTn + og * 8;  // wave-uniform
    #pragma unroll
    for (int u = 0; u < 8; ++u) acc[u] += wr[u] * x;
  }
  float* d = out + bh * OUTn + og * 8;
  #pragma unroll
  for (int u = 0; u < 8; ++u) d[u] = 1.f / (1.f + __expf(-acc[u]));
}

extern "C" void kernel_launch(void* const* d_in, const int* in_sizes, int n_in,
                              void* d_out, int out_size, void* d_ws, size_t ws_size,
                              hipStream_t stream) {
  const float* spec  = (const float*)d_in[0];
  const float* Wq    = (const float*)d_in[1];
  const float* Wk    = (const float*)d_in[2];
  const float* Wv    = (const float*)d_in[3];
  const float* rel_t = (const float*)d_in[4];
  const float* rel_f = (const float*)d_in[5];
  const float* W_lin = (const float*)d_in[6];
  const float* b_lin = (const float*)d_in[7];
  float* out = (float*)d_out;
  float* ws  = (float*)d_ws;

  // prep: 20152 threads
  prep_kernel<<<(Wn*OUTn + 255)/256, 256, 0, stream>>>(Wq, Wk, Wv, rel_t, rel_f, W_lin, ws);
  // main: NPOS = 1832 * 256 exactly
  attn_kernel<<<NPOS/256, 256, 0, stream>>>(spec, ws, out, ws + WS_O);
  // head: 8 bh-chunks * 11 o-groups = 88 blocks
  head_kernel<<<88, 256, 0, stream>>>(ws, b_lin, out);
}